// Round 1
// baseline (473.012 us; speedup 1.0000x reference)
//
#include <hip/hip_runtime.h>

#define N_NODES 100000
#define N_EDGES 1600000
#define FEAT 128

// ---------------- degree count (in-degree by target col) ----------------
__global__ void k_degree(const int* __restrict__ col, int* __restrict__ cnt, int E) {
    int i = blockIdx.x * blockDim.x + threadIdx.x;
    if (i < E) atomicAdd(&cnt[col[i]], 1);
}

// ---------------- exclusive scan of cnt -> starts (3 kernels) ----------------
__global__ void k_scan_block(const int* __restrict__ cnt, int* __restrict__ starts,
                             int* __restrict__ bsums, int n) {
    __shared__ int s[256];
    int tid = threadIdx.x;
    int i = blockIdx.x * 256 + tid;
    int v = (i < n) ? cnt[i] : 0;
    s[tid] = v;
    __syncthreads();
    for (int off = 1; off < 256; off <<= 1) {
        int t = (tid >= off) ? s[tid - off] : 0;
        __syncthreads();
        s[tid] += t;
        __syncthreads();
    }
    if (i < n) starts[i] = s[tid] - v;           // exclusive within block
    if (tid == 255) bsums[blockIdx.x] = s[255];  // block total
}

__global__ void k_scan_sums(int* bsums, int nb) {
    __shared__ int s[512];
    int tid = threadIdx.x;
    int v = (tid < nb) ? bsums[tid] : 0;
    s[tid] = v;
    __syncthreads();
    for (int off = 1; off < 512; off <<= 1) {
        int t = (tid >= off) ? s[tid - off] : 0;
        __syncthreads();
        s[tid] += t;
        __syncthreads();
    }
    if (tid < nb) bsums[tid] = s[tid] - v;       // exclusive
}

__global__ void k_finalize(int* __restrict__ starts, const int* __restrict__ bsums,
                           int* __restrict__ cursors, const int* __restrict__ cnt,
                           float* __restrict__ dinv, int n) {
    int i = blockIdx.x * blockDim.x + threadIdx.x;
    if (i >= n) return;
    int st = starts[i] + bsums[i >> 8];
    starts[i] = st;
    cursors[i] = st;
    dinv[i] = rsqrtf((float)(cnt[i] + 1));  // +1 = self-loop; always > 0
}

// ---------------- CSR fill ----------------
__global__ void k_fill(const int* __restrict__ row, const int* __restrict__ col,
                       int* __restrict__ cursors, int* __restrict__ src_idx, int E) {
    int i = blockIdx.x * blockDim.x + threadIdx.x;
    if (i < E) {
        int c = col[i];
        int pos = atomicAdd(&cursors[c], 1);
        src_idx[pos] = row[i];
    }
}

// ---------------- y = (x @ W) * dinv[row]  (fp32 vector GEMM, W in LDS) ----------------
// block = 256 threads, 32 rows/block, thread = 2 rows x 8 cols.
// LDS: W 64KB + X-tile 16KB = 80KB -> 2 blocks/CU.
__global__ __launch_bounds__(256, 2)
void k_gemm_scale(const float* __restrict__ x, const float* __restrict__ W,
                  const float* __restrict__ dinv, float* __restrict__ y) {
    __shared__ float Ws[FEAT * FEAT];
    __shared__ float Xs[32 * FEAT];
    int tid = threadIdx.x;

    const float4* W4 = (const float4*)W;
    float4* Ws4 = (float4*)Ws;
#pragma unroll
    for (int k = 0; k < FEAT * FEAT / 4; k += 256) Ws4[k + tid] = W4[k + tid];

    int rowBase = blockIdx.x * 32;
    const float4* X4 = (const float4*)(x + (size_t)rowBase * FEAT);
    float4* Xs4 = (float4*)Xs;
#pragma unroll
    for (int k = 0; k < 32 * FEAT / 4; k += 256) Xs4[k + tid] = X4[k + tid];
    __syncthreads();

    int r0 = (tid >> 4) * 2;
    int c0 = (tid & 15) * 8;

    float4 acc00 = {0.f, 0.f, 0.f, 0.f}, acc01 = {0.f, 0.f, 0.f, 0.f};
    float4 acc10 = {0.f, 0.f, 0.f, 0.f}, acc11 = {0.f, 0.f, 0.f, 0.f};

    const float* xrA = &Xs[r0 * FEAT];
    const float* xrB = &Xs[(r0 + 1) * FEAT];

#pragma unroll 4
    for (int k = 0; k < FEAT; ++k) {
        const float4 w0 = *(const float4*)&Ws[k * FEAT + c0];
        const float4 w1 = *(const float4*)&Ws[k * FEAT + c0 + 4];
        const float xa = xrA[k];
        const float xb = xrB[k];
        acc00.x += xa * w0.x; acc00.y += xa * w0.y; acc00.z += xa * w0.z; acc00.w += xa * w0.w;
        acc01.x += xa * w1.x; acc01.y += xa * w1.y; acc01.z += xa * w1.z; acc01.w += xa * w1.w;
        acc10.x += xb * w0.x; acc10.y += xb * w0.y; acc10.z += xb * w0.z; acc10.w += xb * w0.w;
        acc11.x += xb * w1.x; acc11.y += xb * w1.y; acc11.z += xb * w1.z; acc11.w += xb * w1.w;
    }

    float da = dinv[rowBase + r0];
    float db = dinv[rowBase + r0 + 1];
    float4* ya = (float4*)(y + (size_t)(rowBase + r0) * FEAT + c0);
    float4* yb = (float4*)(y + (size_t)(rowBase + r0 + 1) * FEAT + c0);
    ya[0] = make_float4(acc00.x * da, acc00.y * da, acc00.z * da, acc00.w * da);
    ya[1] = make_float4(acc01.x * da, acc01.y * da, acc01.z * da, acc01.w * da);
    yb[0] = make_float4(acc10.x * db, acc10.y * db, acc10.z * db, acc10.w * db);
    yb[1] = make_float4(acc11.x * db, acc11.y * db, acc11.z * db, acc11.w * db);
}

// ---------------- aggregation: out[i] = b + dinv[i]*(y[i] + sum y[src]) ----------------
// 32 lanes x float4 per node, 8 nodes per 256-thread block.
__global__ __launch_bounds__(256)
void k_aggregate(const float* __restrict__ y, const int* __restrict__ starts,
                 const int* __restrict__ cnt, const int* __restrict__ src_idx,
                 const float* __restrict__ dinv, const float* __restrict__ b,
                 float* __restrict__ out, int n) {
    int node = blockIdx.x * 8 + (threadIdx.x >> 5);
    int lane = threadIdx.x & 31;
    if (node >= n) return;

    const float4* y4 = (const float4*)y;
    float4 acc = y4[(size_t)node * 32 + lane];  // self-loop term (y already * dinv)
    int st = starts[node];
    int c = cnt[node];
    for (int j = 0; j < c; ++j) {
        int src = src_idx[st + j];
        float4 v = y4[(size_t)src * 32 + lane];
        acc.x += v.x; acc.y += v.y; acc.z += v.z; acc.w += v.w;
    }
    float d = dinv[node];
    float4 bb = ((const float4*)b)[lane];
    float4 o;
    o.x = bb.x + d * acc.x;
    o.y = bb.y + d * acc.y;
    o.z = bb.z + d * acc.z;
    o.w = bb.w + d * acc.w;
    ((float4*)out)[(size_t)node * 32 + lane] = o;
}

extern "C" void kernel_launch(void* const* d_in, const int* in_sizes, int n_in,
                              void* d_out, int out_size, void* d_ws, size_t ws_size,
                              hipStream_t stream) {
    const float* x = (const float*)d_in[0];
    const float* W = (const float*)d_in[1];
    const float* b = (const float*)d_in[2];
    const int* ei = (const int*)d_in[3];
    const int* row = ei;             // edge_index[0] = source
    const int* col = ei + N_EDGES;   // edge_index[1] = target
    float* out = (float*)d_out;

    char* ws = (char*)d_ws;
    size_t off = 0;
    auto alloc = [&](size_t bytes) -> void* {
        void* p = ws + off;
        off += (bytes + 511) & ~(size_t)511;
        return p;
    };
    int* cnt      = (int*)alloc((size_t)N_NODES * 4);
    int* starts   = (int*)alloc((size_t)N_NODES * 4);
    int* cursors  = (int*)alloc((size_t)N_NODES * 4);
    int* bsums    = (int*)alloc(512 * 4);
    float* dinv   = (float*)alloc((size_t)N_NODES * 4);
    int* src_idx  = (int*)alloc((size_t)N_EDGES * 4);
    float* y      = (float*)alloc((size_t)N_NODES * FEAT * 4);

    hipMemsetAsync(cnt, 0, (size_t)N_NODES * 4, stream);

    k_degree<<<(N_EDGES + 255) / 256, 256, 0, stream>>>(col, cnt, N_EDGES);

    int nb = (N_NODES + 255) / 256;  // 391
    k_scan_block<<<nb, 256, 0, stream>>>(cnt, starts, bsums, N_NODES);
    k_scan_sums<<<1, 512, 0, stream>>>(bsums, nb);
    k_finalize<<<nb, 256, 0, stream>>>(starts, bsums, cursors, cnt, dinv, N_NODES);

    k_fill<<<(N_EDGES + 255) / 256, 256, 0, stream>>>(row, col, cursors, src_idx, N_EDGES);

    k_gemm_scale<<<N_NODES / 32, 256, 0, stream>>>(x, W, dinv, y);

    k_aggregate<<<(N_NODES + 7) / 8, 256, 0, stream>>>(y, starts, cnt, src_idx, dinv, b, out, N_NODES);
}

// Round 2
// 391.240 us; speedup vs baseline: 1.2090x; 1.2090x over previous
//
#include <hip/hip_runtime.h>

#define N_NODES 100000
#define N_EDGES 1600000
#define FEAT 128
#define N_PAD 100032  // padded to multiple of 64 rows for the GEMM tile

typedef __attribute__((ext_vector_type(8))) short short8;
typedef __attribute__((ext_vector_type(4))) float f32x4;

__device__ inline unsigned short f2bf(float f) {
    unsigned u = __builtin_bit_cast(unsigned, f);
    unsigned r = (u + 0x7FFFu + ((u >> 16) & 1u)) >> 16;  // RNE
    return (unsigned short)r;
}
__device__ inline float bf2f(unsigned h) {
    unsigned u = h << 16;
    return __builtin_bit_cast(float, u);
}

// ---------------- fused: degree atomics + x->bf16 convert + Wt (transposed bf16 W) ----
#define DEG_BLOCKS 6250   // 1.6M / 256
#define CONV_BLOCKS 6252  // N_PAD*128 / 2048
__global__ __launch_bounds__(256)
void k_pre(const int* __restrict__ col, int* __restrict__ cnt,
           const float* __restrict__ x, const float* __restrict__ W,
           unsigned short* __restrict__ xb, unsigned short* __restrict__ Wt) {
    int bid = blockIdx.x, tid = threadIdx.x;
    if (bid < DEG_BLOCKS) {
        int i = bid * 256 + tid;
        if (i < N_EDGES) atomicAdd(&cnt[col[i]], 1);
    } else if (bid < DEG_BLOCKS + CONV_BLOCKS) {
        size_t base = (size_t)(bid - DEG_BLOCKS) * 2048 + (size_t)tid * 8;
        short8 o;
        if (base < (size_t)N_NODES * FEAT) {
            const float4* p = (const float4*)(x + base);
            float4 a = p[0], c = p[1];
            o[0] = (short)f2bf(a.x); o[1] = (short)f2bf(a.y);
            o[2] = (short)f2bf(a.z); o[3] = (short)f2bf(a.w);
            o[4] = (short)f2bf(c.x); o[5] = (short)f2bf(c.y);
            o[6] = (short)f2bf(c.z); o[7] = (short)f2bf(c.w);
        } else {
            for (int j = 0; j < 8; ++j) o[j] = 0;
        }
        *(short8*)(xb + base) = o;
    } else {
        // one block: build Wt[n][k] = bf16(W[k][n])
        for (int it = 0; it < (FEAT * FEAT) / 256; ++it) {
            int idx = it * 256 + tid;
            int k = idx >> 7, n = idx & 127;
            Wt[n * FEAT + k] = f2bf(W[idx]);
        }
    }
}

// ---------------- exclusive scan of cnt -> starts (3 kernels) ----------------
__global__ void k_scan_block(const int* __restrict__ cnt, int* __restrict__ starts,
                             int* __restrict__ bsums, int n) {
    __shared__ int s[256];
    int tid = threadIdx.x;
    int i = blockIdx.x * 256 + tid;
    int v = (i < n) ? cnt[i] : 0;
    s[tid] = v;
    __syncthreads();
    for (int off = 1; off < 256; off <<= 1) {
        int t = (tid >= off) ? s[tid - off] : 0;
        __syncthreads();
        s[tid] += t;
        __syncthreads();
    }
    if (i < n) starts[i] = s[tid] - v;
    if (tid == 255) bsums[blockIdx.x] = s[255];
}

__global__ void k_scan_sums(int* bsums, int nb) {
    __shared__ int s[512];
    int tid = threadIdx.x;
    int v = (tid < nb) ? bsums[tid] : 0;
    s[tid] = v;
    __syncthreads();
    for (int off = 1; off < 512; off <<= 1) {
        int t = (tid >= off) ? s[tid - off] : 0;
        __syncthreads();
        s[tid] += t;
        __syncthreads();
    }
    if (tid < nb) bsums[tid] = s[tid] - v;
}

__global__ void k_finalize(int* __restrict__ starts, const int* __restrict__ bsums,
                           int* __restrict__ cursors, const int* __restrict__ cnt,
                           float* __restrict__ dinv, int n) {
    int i = blockIdx.x * blockDim.x + threadIdx.x;
    if (i >= n) return;
    int st = starts[i] + bsums[i >> 8];
    starts[i] = st;
    cursors[i] = st;
    dinv[i] = rsqrtf((float)(cnt[i] + 1));  // +1 self-loop
}

// ---------------- fused: MFMA bf16 GEMM (y = (x@W)*dinv, bf16 out) + CSR fill ------
// GEMM blocks first (compute-bound, hide under line-bound fill blocks).
#define GEMM_BLOCKS 1563  // ceil(100000/64)
#define FILL_BLOCKS 6250
__global__ __launch_bounds__(256)
void k_fill_gemm(const int* __restrict__ row, const int* __restrict__ col,
                 int* __restrict__ cursors, int* __restrict__ src_idx,
                 const unsigned short* __restrict__ xb,
                 const unsigned short* __restrict__ Wt,
                 const float* __restrict__ dinv, unsigned short* __restrict__ yb) {
    int bid = blockIdx.x, tid = threadIdx.x;
    if (bid >= GEMM_BLOCKS) {
        int i = (bid - GEMM_BLOCKS) * 256 + tid;
        if (i < N_EDGES) {
            int c = col[i];
            int pos = atomicAdd(&cursors[c], 1);
            src_idx[pos] = row[i];
        }
        return;
    }
    // GEMM: wave computes 16 rows x 128 cols. Block = 4 waves = 64 rows.
    int lane = tid & 63;
    int m = lane & 15, quad = lane >> 4;
    int rowBase = bid * 64 + (tid >> 6) * 16;
    const unsigned short* xr = xb + (size_t)(rowBase + m) * FEAT + quad * 8;

    f32x4 acc[8];
#pragma unroll
    for (int nt = 0; nt < 8; ++nt) acc[nt] = (f32x4){0.f, 0.f, 0.f, 0.f};

#pragma unroll
    for (int kk = 0; kk < 4; ++kk) {
        short8 a = *(const short8*)(xr + kk * 32);
        const unsigned short* wp = Wt + m * FEAT + kk * 32 + quad * 8;
#pragma unroll
        for (int nt = 0; nt < 8; ++nt) {
            short8 bf = *(const short8*)(wp + nt * 16 * FEAT);
            acc[nt] = __builtin_amdgcn_mfma_f32_16x16x32_bf16(a, bf, acc[nt], 0, 0, 0);
        }
    }

    // epilogue: C/D layout col=lane&15, row=quad*4+reg
    int r0 = rowBase + quad * 4;
    float d[4];
#pragma unroll
    for (int r = 0; r < 4; ++r) d[r] = (r0 + r < N_NODES) ? dinv[r0 + r] : 0.f;
#pragma unroll
    for (int nt = 0; nt < 8; ++nt) {
        int cc = nt * 16 + m;
#pragma unroll
        for (int r = 0; r < 4; ++r) {
            int rr = r0 + r;
            if (rr < N_NODES) yb[(size_t)rr * FEAT + cc] = f2bf(acc[nt][r] * d[r]);
        }
    }
}

// ---------------- aggregation: out[i] = b + dinv[i]*(y[i] + sum y[src]) ----------
// 32 lanes x 4 bf16 (8B) per node, 8 nodes per 256-thread block, fp32 accumulate.
__global__ __launch_bounds__(256)
void k_aggregate(const unsigned short* __restrict__ yb, const int* __restrict__ starts,
                 const int* __restrict__ cnt, const int* __restrict__ src_idx,
                 const float* __restrict__ dinv, const float* __restrict__ b,
                 float* __restrict__ out) {
    int node = blockIdx.x * 8 + (threadIdx.x >> 5);
    int lane = threadIdx.x & 31;
    if (node >= N_NODES) return;

    const uint2* y2 = (const uint2*)yb;
    uint2 s = y2[(size_t)node * 32 + lane];  // self term (already * dinv_src)
    float a0 = bf2f(s.x & 0xFFFFu), a1 = bf2f(s.x >> 16);
    float a2 = bf2f(s.y & 0xFFFFu), a3 = bf2f(s.y >> 16);

    int st = starts[node], c = cnt[node];
    for (int j = 0; j < c; ++j) {
        int src = src_idx[st + j];
        uint2 v = y2[(size_t)src * 32 + lane];
        a0 += bf2f(v.x & 0xFFFFu); a1 += bf2f(v.x >> 16);
        a2 += bf2f(v.y & 0xFFFFu); a3 += bf2f(v.y >> 16);
    }
    float dd = dinv[node];
    float4 bb = ((const float4*)b)[lane];
    float4 o = make_float4(bb.x + dd * a0, bb.y + dd * a1,
                           bb.z + dd * a2, bb.w + dd * a3);
    ((float4*)out)[(size_t)node * 32 + lane] = o;
}

extern "C" void kernel_launch(void* const* d_in, const int* in_sizes, int n_in,
                              void* d_out, int out_size, void* d_ws, size_t ws_size,
                              hipStream_t stream) {
    const float* x = (const float*)d_in[0];
    const float* W = (const float*)d_in[1];
    const float* b = (const float*)d_in[2];
    const int* ei = (const int*)d_in[3];
    const int* row = ei;            // edge_index[0] = source
    const int* col = ei + N_EDGES;  // edge_index[1] = target
    float* out = (float*)d_out;

    char* ws = (char*)d_ws;
    size_t off = 0;
    auto alloc = [&](size_t bytes) -> void* {
        void* p = ws + off;
        off += (bytes + 511) & ~(size_t)511;
        return p;
    };
    int* cnt            = (int*)alloc((size_t)N_NODES * 4);
    int* starts         = (int*)alloc((size_t)N_NODES * 4);
    int* cursors        = (int*)alloc((size_t)N_NODES * 4);
    int* bsums          = (int*)alloc(512 * 4);
    float* dinv         = (float*)alloc((size_t)N_NODES * 4);
    int* src_idx        = (int*)alloc((size_t)N_EDGES * 4);
    unsigned short* xb  = (unsigned short*)alloc((size_t)N_PAD * FEAT * 2);
    unsigned short* Wt  = (unsigned short*)alloc((size_t)FEAT * FEAT * 2);
    unsigned short* yb  = (unsigned short*)alloc((size_t)N_NODES * FEAT * 2);

    hipMemsetAsync(cnt, 0, (size_t)N_NODES * 4, stream);

    k_pre<<<DEG_BLOCKS + CONV_BLOCKS + 1, 256, 0, stream>>>(col, cnt, x, W, xb, Wt);

    int nb = (N_NODES + 255) / 256;  // 391
    k_scan_block<<<nb, 256, 0, stream>>>(cnt, starts, bsums, N_NODES);
    k_scan_sums<<<1, 512, 0, stream>>>(bsums, nb);
    k_finalize<<<nb, 256, 0, stream>>>(starts, bsums, cursors, cnt, dinv, N_NODES);

    k_fill_gemm<<<GEMM_BLOCKS + FILL_BLOCKS, 256, 0, stream>>>(
        row, col, cursors, src_idx, xb, Wt, dinv, yb);

    k_aggregate<<<(N_NODES + 7) / 8, 256, 0, stream>>>(yb, starts, cnt, src_idx, dinv, b, out);
}

// Round 3
// 237.218 us; speedup vs baseline: 1.9940x; 1.6493x over previous
//
#include <hip/hip_runtime.h>

#define N_NODES 100000
#define N_EDGES 1600000
#define FEAT 128
#define NBUCK 782        // ceil(100000/128) buckets of 128 target nodes
#define BUCK_SHIFT 7
#define BUCK_MASK 127
#define GEMM_BLOCKS 1563 // ceil(100000/64)
#define HIST_EPB 4096
#define HIST_BLOCKS 391  // ceil(1.6M/4096)
#define WT_PITCH 136     // 128 + 8 pad: keeps 16B alignment, balances LDS banks

typedef __attribute__((ext_vector_type(8))) short short8;
typedef __attribute__((ext_vector_type(4))) float f32x4;

__device__ inline unsigned short f2bf(float f) {
    unsigned u = __builtin_bit_cast(unsigned, f);
    unsigned r = (u + 0x7FFFu + ((u >> 16) & 1u)) >> 16;  // RNE
    return (unsigned short)r;
}
__device__ inline float bf2f(unsigned h) {
    unsigned u = h << 16;
    return __builtin_bit_cast(float, u);
}

// ============ fused: MFMA GEMM (yraw = bf16(x@W), unscaled) + bucket histogram ======
// GEMM blocks read x fp32, convert in-register, MFMA vs W staged transposed in LDS.
// Hist blocks (atomic/L2 pipe) co-schedule with GEMM blocks (MFMA/HBM pipe).
__global__ __launch_bounds__(256)
void k_gemm_hist(const float* __restrict__ x, const float* __restrict__ W,
                 unsigned short* __restrict__ yb,
                 const int* __restrict__ col, int* __restrict__ bcnt) {
    int bid = blockIdx.x, tid = threadIdx.x;
    if (bid >= GEMM_BLOCKS) {
        __shared__ int hist[NBUCK];
        for (int i = tid; i < NBUCK; i += 256) hist[i] = 0;
        __syncthreads();
        int e0 = (bid - GEMM_BLOCKS) * HIST_EPB;
        int n = min(HIST_EPB, N_EDGES - e0);
        for (int i = tid * 4; i < n; i += 1024) {
            if (i + 3 < n) {
                int4 c4 = *(const int4*)(col + e0 + i);
                atomicAdd(&hist[c4.x >> BUCK_SHIFT], 1);
                atomicAdd(&hist[c4.y >> BUCK_SHIFT], 1);
                atomicAdd(&hist[c4.z >> BUCK_SHIFT], 1);
                atomicAdd(&hist[c4.w >> BUCK_SHIFT], 1);
            } else {
                for (int j = i; j < n; ++j) atomicAdd(&hist[col[e0 + j] >> BUCK_SHIFT], 1);
            }
        }
        __syncthreads();
        for (int i = tid; i < NBUCK; i += 256) {
            int h = hist[i];
            if (h) atomicAdd(&bcnt[i], h);
        }
        return;
    }

    __shared__ unsigned short Ws[FEAT * WT_PITCH];  // Wt[n][k] = bf16(W[k][n])
    for (int idx = tid; idx < FEAT * FEAT; idx += 256) {
        int k = idx >> 7, n = idx & 127;
        Ws[n * WT_PITCH + k] = f2bf(W[idx]);
    }
    __syncthreads();

    int lane = tid & 63;
    int m = lane & 15, quad = lane >> 4;
    int rowBase = bid * 64 + (tid >> 6) * 16;
    int arow = rowBase + m;
    if (arow >= N_NODES) arow = N_NODES - 1;  // clamp OOB A-reads; stores guarded
    const float* xr = x + (size_t)arow * FEAT + quad * 8;

    f32x4 acc[8];
#pragma unroll
    for (int nt = 0; nt < 8; ++nt) acc[nt] = (f32x4){0.f, 0.f, 0.f, 0.f};

#pragma unroll
    for (int kk = 0; kk < 4; ++kk) {
        float4 xa = *(const float4*)(xr + kk * 32);
        float4 xc = *(const float4*)(xr + kk * 32 + 4);
        short8 a;
        a[0] = (short)f2bf(xa.x); a[1] = (short)f2bf(xa.y);
        a[2] = (short)f2bf(xa.z); a[3] = (short)f2bf(xa.w);
        a[4] = (short)f2bf(xc.x); a[5] = (short)f2bf(xc.y);
        a[6] = (short)f2bf(xc.z); a[7] = (short)f2bf(xc.w);
        const unsigned short* wp = Ws + m * WT_PITCH + kk * 32 + quad * 8;
#pragma unroll
        for (int nt = 0; nt < 8; ++nt) {
            short8 bf = *(const short8*)(wp + nt * 16 * WT_PITCH);
            acc[nt] = __builtin_amdgcn_mfma_f32_16x16x32_bf16(a, bf, acc[nt], 0, 0, 0);
        }
    }

    int r0 = rowBase + quad * 4;  // C/D: col = nt*16 + m, row = quad*4 + r
#pragma unroll
    for (int nt = 0; nt < 8; ++nt) {
        int cc = nt * 16 + m;
#pragma unroll
        for (int r = 0; r < 4; ++r) {
            int rr = r0 + r;
            if (rr < N_NODES) yb[(size_t)rr * FEAT + cc] = f2bf(acc[nt][r]);
        }
    }
}

// ============ exclusive scan over 782 bucket counts (1 block) ======================
__global__ __launch_bounds__(1024)
void k_bscan(const int* __restrict__ bcnt, int* __restrict__ bstarts,
             int* __restrict__ bcursor) {
    __shared__ int s[1024];
    int tid = threadIdx.x;
    int v = (tid < NBUCK) ? bcnt[tid] : 0;
    s[tid] = v;
    __syncthreads();
    for (int off = 1; off < 1024; off <<= 1) {
        int t = (tid >= off) ? s[tid - off] : 0;
        __syncthreads();
        s[tid] += t;
        __syncthreads();
    }
    if (tid < NBUCK) {
        int ex = s[tid] - v;
        bstarts[tid] = ex;
        bcursor[tid] = ex;
    }
    if (tid == NBUCK - 1) bstarts[NBUCK] = s[tid];
}

// ============ bucket scatter: pack (src<<7 | tgt&127) into bucket-ordered ebuf =====
// Write frontier = 782 sequential streams -> ~50KB of hot lines, L2-absorbed.
__global__ __launch_bounds__(256)
void k_bscatter(const int* __restrict__ row, const int* __restrict__ col,
                int* __restrict__ bcursor, unsigned* __restrict__ ebuf) {
    __shared__ int hist[NBUCK];
    __shared__ int gbase[NBUCK];
    int tid = threadIdx.x;
    for (int i = tid; i < NBUCK; i += 256) hist[i] = 0;
    __syncthreads();
    int e0 = blockIdx.x * HIST_EPB;
    int n = min(HIST_EPB, N_EDGES - e0);
    for (int i = tid * 4; i < n; i += 1024) {
        if (i + 3 < n) {
            int4 c4 = *(const int4*)(col + e0 + i);
            atomicAdd(&hist[c4.x >> BUCK_SHIFT], 1);
            atomicAdd(&hist[c4.y >> BUCK_SHIFT], 1);
            atomicAdd(&hist[c4.z >> BUCK_SHIFT], 1);
            atomicAdd(&hist[c4.w >> BUCK_SHIFT], 1);
        } else {
            for (int j = i; j < n; ++j) atomicAdd(&hist[col[e0 + j] >> BUCK_SHIFT], 1);
        }
    }
    __syncthreads();
    for (int i = tid; i < NBUCK; i += 256) {
        int h = hist[i];
        gbase[i] = h ? atomicAdd(&bcursor[i], h) : 0;
    }
    __syncthreads();
    for (int i = tid; i < NBUCK; i += 256) hist[i] = 0;  // reuse as local cursor
    __syncthreads();
    for (int i = tid * 4; i < n; i += 1024) {
        if (i + 3 < n) {
            int4 c4 = *(const int4*)(col + e0 + i);
            int4 r4 = *(const int4*)(row + e0 + i);
            int bk, off;
            bk = c4.x >> BUCK_SHIFT; off = atomicAdd(&hist[bk], 1);
            ebuf[gbase[bk] + off] = ((unsigned)r4.x << BUCK_SHIFT) | (unsigned)(c4.x & BUCK_MASK);
            bk = c4.y >> BUCK_SHIFT; off = atomicAdd(&hist[bk], 1);
            ebuf[gbase[bk] + off] = ((unsigned)r4.y << BUCK_SHIFT) | (unsigned)(c4.y & BUCK_MASK);
            bk = c4.z >> BUCK_SHIFT; off = atomicAdd(&hist[bk], 1);
            ebuf[gbase[bk] + off] = ((unsigned)r4.z << BUCK_SHIFT) | (unsigned)(c4.z & BUCK_MASK);
            bk = c4.w >> BUCK_SHIFT; off = atomicAdd(&hist[bk], 1);
            ebuf[gbase[bk] + off] = ((unsigned)r4.w << BUCK_SHIFT) | (unsigned)(c4.w & BUCK_MASK);
        } else {
            for (int j = i; j < n; ++j) {
                int c = col[e0 + j], r = row[e0 + j];
                int bk = c >> BUCK_SHIFT;
                int off = atomicAdd(&hist[bk], 1);
                ebuf[gbase[bk] + off] = ((unsigned)r << BUCK_SHIFT) | (unsigned)(c & BUCK_MASK);
            }
        }
    }
}

// ============ per-bucket CSR: LDS hist + scan -> starts/dinv, LDS-cursor fill ======
__global__ __launch_bounds__(256)
void k_csr(const unsigned* __restrict__ ebuf, const int* __restrict__ bstarts,
           int* __restrict__ starts, float* __restrict__ dinv,
           int* __restrict__ src_idx) {
    __shared__ int hist[128];
    __shared__ int scan[128];
    __shared__ int cur[128];
    int b = blockIdx.x, tid = threadIdx.x;
    int node0 = b << BUCK_SHIFT;
    int nnodes = min(128, N_NODES - node0);
    if (tid < 128) hist[tid] = 0;
    __syncthreads();
    int e0 = bstarts[b], e1 = bstarts[b + 1];
    int ne = e1 - e0;
    for (int i = tid; i < ne; i += 256) atomicAdd(&hist[ebuf[e0 + i] & BUCK_MASK], 1);
    __syncthreads();
    if (tid < 128) scan[tid] = hist[tid];
    __syncthreads();
    for (int off = 1; off < 128; off <<= 1) {
        int t = 0;
        if (tid < 128 && tid >= off) t = scan[tid - off];
        __syncthreads();
        if (tid < 128) scan[tid] += t;
        __syncthreads();
    }
    if (tid < 128) {
        int ex = scan[tid] - hist[tid];
        cur[tid] = ex;
        if (tid < nnodes) {
            starts[node0 + tid] = e0 + ex;
            dinv[node0 + tid] = rsqrtf((float)(hist[tid] + 1));  // +1 self-loop
        }
    }
    if (b == 0 && tid == 0) starts[N_NODES] = N_EDGES;  // sentinel
    __syncthreads();
    for (int i = tid; i < ne; i += 256) {
        unsigned e = ebuf[e0 + i];
        int pos = atomicAdd(&cur[e & BUCK_MASK], 1);
        src_idx[e0 + pos] = (int)(e >> BUCK_SHIFT);
    }
}

// ============ aggregate: out[i] = b + dinv[i]*(dinv[i]*y[i] + sum dinv[s]*y[s]) ====
// One wave per node: 64 lanes x 2 bf16 feats; srcs batch-loaded + shfl-broadcast.
__global__ __launch_bounds__(256)
void k_agg(const unsigned short* __restrict__ yb, const int* __restrict__ starts,
           const int* __restrict__ src_idx, const float* __restrict__ dinv,
           const float* __restrict__ bias, float* __restrict__ out) {
    int node = blockIdx.x * 4 + (threadIdx.x >> 6);
    int lane = threadIdx.x & 63;
    if (node >= N_NODES) return;
    int st = starts[node], en = starts[node + 1];
    float di = dinv[node];
    const unsigned* y1 = (const unsigned*)yb;  // 2 bf16 per uint
    unsigned sv = y1[(size_t)node * 64 + lane];
    float a0 = di * bf2f(sv & 0xFFFFu);
    float a1 = di * bf2f(sv >> 16);
    for (int base = st; base < en; base += 64) {
        int nn = min(64, en - base);
        int src = 0;
        float dv = 0.f;
        if (lane < nn) {
            src = src_idx[base + lane];
            dv = dinv[src];
        }
        int j = 0;
        for (; j + 3 < nn; j += 4) {
            int s0 = __shfl(src, j),     s1 = __shfl(src, j + 1);
            int s2 = __shfl(src, j + 2), s3 = __shfl(src, j + 3);
            float d0 = __shfl(dv, j),     d1 = __shfl(dv, j + 1);
            float d2 = __shfl(dv, j + 2), d3 = __shfl(dv, j + 3);
            unsigned v0 = y1[(size_t)s0 * 64 + lane];
            unsigned v1 = y1[(size_t)s1 * 64 + lane];
            unsigned v2 = y1[(size_t)s2 * 64 + lane];
            unsigned v3 = y1[(size_t)s3 * 64 + lane];
            a0 += d0 * bf2f(v0 & 0xFFFFu); a1 += d0 * bf2f(v0 >> 16);
            a0 += d1 * bf2f(v1 & 0xFFFFu); a1 += d1 * bf2f(v1 >> 16);
            a0 += d2 * bf2f(v2 & 0xFFFFu); a1 += d2 * bf2f(v2 >> 16);
            a0 += d3 * bf2f(v3 & 0xFFFFu); a1 += d3 * bf2f(v3 >> 16);
        }
        for (; j < nn; ++j) {
            int s = __shfl(src, j);
            float d = __shfl(dv, j);
            unsigned v = y1[(size_t)s * 64 + lane];
            a0 += d * bf2f(v & 0xFFFFu);
            a1 += d * bf2f(v >> 16);
        }
    }
    float2 bb = ((const float2*)bias)[lane];
    float2 o;
    o.x = bb.x + di * a0;
    o.y = bb.y + di * a1;
    ((float2*)out)[(size_t)node * 64 + lane] = o;
}

extern "C" void kernel_launch(void* const* d_in, const int* in_sizes, int n_in,
                              void* d_out, int out_size, void* d_ws, size_t ws_size,
                              hipStream_t stream) {
    const float* x = (const float*)d_in[0];
    const float* W = (const float*)d_in[1];
    const float* b = (const float*)d_in[2];
    const int* ei = (const int*)d_in[3];
    const int* row = ei;            // edge_index[0] = source
    const int* col = ei + N_EDGES;  // edge_index[1] = target
    float* out = (float*)d_out;

    char* ws = (char*)d_ws;
    size_t off = 0;
    auto alloc = [&](size_t bytes) -> void* {
        void* p = ws + off;
        off += (bytes + 511) & ~(size_t)511;
        return p;
    };
    int* bcnt          = (int*)alloc((NBUCK + 1) * 4);
    int* bstarts       = (int*)alloc((NBUCK + 1) * 4);
    int* bcursor       = (int*)alloc((NBUCK + 1) * 4);
    int* starts        = (int*)alloc((size_t)(N_NODES + 1) * 4);
    float* dinv        = (float*)alloc((size_t)N_NODES * 4);
    unsigned* ebuf     = (unsigned*)alloc((size_t)N_EDGES * 4);
    int* src_idx       = (int*)alloc((size_t)N_EDGES * 4);
    unsigned short* yb = (unsigned short*)alloc((size_t)N_NODES * FEAT * 2);

    hipMemsetAsync(bcnt, 0, (NBUCK + 1) * 4, stream);

    k_gemm_hist<<<GEMM_BLOCKS + HIST_BLOCKS, 256, 0, stream>>>(x, W, yb, col, bcnt);
    k_bscan<<<1, 1024, 0, stream>>>(bcnt, bstarts, bcursor);
    k_bscatter<<<HIST_BLOCKS, 256, 0, stream>>>(row, col, bcursor, ebuf);
    k_csr<<<NBUCK, 256, 0, stream>>>(ebuf, bstarts, starts, dinv, src_idx);
    k_agg<<<(N_NODES + 3) / 4, 256, 0, stream>>>(yb, starts, src_idx, dinv, b, out);
}